// Round 1
// baseline (631.433 us; speedup 1.0000x reference)
//
#include <hip/hip_runtime.h>
#include <hip/hip_bf16.h>

// GCN 2-layer: h = relu(Agg(x@W1)+b1); out = log_softmax(Agg(h@W2)+b2)
// Agg = D^-1/2 (A+I) D^-1/2 scatter with dst-degree normalization.
// Strategy: build CSR by dst once (count -> scan -> fill), then per-node
// gather-sum (no float atomics), aggregation done on post-GEMM features.

#define N_NODES 100000

// ---------------- CSR build ----------------

__global__ void k_count(const int* __restrict__ dst, int E, int* __restrict__ cnt) {
    for (int e = blockIdx.x * blockDim.x + threadIdx.x; e < E; e += gridDim.x * blockDim.x)
        atomicAdd(&cnt[dst[e]], 1);
}

// per-block exclusive scan of cnt -> rowptr (local), block sums -> partial; also dinv = rsqrt(cnt+1)
__global__ void k_scanA(const int* __restrict__ cnt, int n, int* __restrict__ rowptr,
                        int* __restrict__ partial, float* __restrict__ dinv) {
    __shared__ int s[256];
    int t = threadIdx.x;
    int i = blockIdx.x * 256 + t;
    int v = (i < n) ? cnt[i] : 0;
    if (i < n) dinv[i] = rsqrtf((float)(v + 1));   // +1 self-loop; always > 0
    s[t] = v;
    __syncthreads();
    for (int off = 1; off < 256; off <<= 1) {
        int add = (t >= off) ? s[t - off] : 0;
        __syncthreads();
        s[t] += add;
        __syncthreads();
    }
    if (i < n) rowptr[i] = s[t] - v;               // exclusive
    if (t == 255) partial[blockIdx.x] = s[255];
}

__global__ void k_scanB(int* __restrict__ partial, int nb) {
    __shared__ int s[512];
    int t = threadIdx.x;
    int v = (t < nb) ? partial[t] : 0;
    s[t] = v;
    __syncthreads();
    for (int off = 1; off < 512; off <<= 1) {
        int add = (t >= off) ? s[t - off] : 0;
        __syncthreads();
        s[t] += add;
        __syncthreads();
    }
    if (t < nb) partial[t] = s[t] - v;             // exclusive block offsets
}

__global__ void k_scanC(int* __restrict__ rowptr, const int* __restrict__ partial, int n, int E) {
    int i = blockIdx.x * 256 + threadIdx.x;
    if (i < n) rowptr[i] += partial[blockIdx.x];
    if (i == 0) rowptr[n] = E;
}

__global__ void k_fill(const int* __restrict__ src, const int* __restrict__ dst, int E,
                       const int* __restrict__ rowptr, int* __restrict__ fill,
                       int* __restrict__ csrc) {
    for (int e = blockIdx.x * blockDim.x + threadIdx.x; e < E; e += gridDim.x * blockDim.x) {
        int d = dst[e];
        int pos = rowptr[d] + atomicAdd(&fill[d], 1);
        csrc[pos] = src[e];
    }
}

// ---------------- GEMM1: [n,256] @ [256,64] ----------------
// 256 rows/block; x tile staged in LDS (pad 33 -> conflict-free); W row loads
// are wave-uniform -> scalar K$ loads.

__global__ __launch_bounds__(256) void k_gemm1(const float* __restrict__ x,
                                               const float* __restrict__ W,
                                               float* __restrict__ out, int n) {
    __shared__ float xt[256 * 33];
    int t = threadIdx.x;
    int rowBase = blockIdx.x * 256;
    int row = rowBase + t;
    float acc[64];
#pragma unroll
    for (int j = 0; j < 64; ++j) acc[j] = 0.f;

    for (int kc = 0; kc < 256; kc += 32) {
        __syncthreads();  // protect previous iteration's reads
#pragma unroll
        for (int it = 0; it < 8; ++it) {
            int f4 = t + it * 256;       // 0..2047 float4s of the 256x32 tile
            int r  = f4 >> 3;            // 8 float4 per row-chunk
            int c4 = f4 & 7;
            int gr = rowBase + r;
            float4 v = make_float4(0.f, 0.f, 0.f, 0.f);
            if (gr < n)
                v = *reinterpret_cast<const float4*>(&x[(size_t)gr * 256 + kc + c4 * 4]);
            float* dp = &xt[r * 33 + c4 * 4];
            dp[0] = v.x; dp[1] = v.y; dp[2] = v.z; dp[3] = v.w;
        }
        __syncthreads();
#pragma unroll
        for (int k = 0; k < 32; ++k) {
            float xv = xt[t * 33 + k];
            const float* wr = &W[(size_t)(kc + k) * 64];
#pragma unroll
            for (int j = 0; j < 64; ++j) acc[j] = fmaf(xv, wr[j], acc[j]);
        }
    }
    if (row < n) {
        float* op = &out[(size_t)row * 64];
#pragma unroll
        for (int j = 0; j < 64; j += 4) {
            float4 v = {acc[j], acc[j + 1], acc[j + 2], acc[j + 3]};
            *reinterpret_cast<float4*>(&op[j]) = v;
        }
    }
}

// ---------------- Aggregation L1 (64-wide) + bias + relu ----------------
// one wave per node, lane = feature

__global__ __launch_bounds__(256) void k_agg1(const float* __restrict__ xl,
                                              const int* __restrict__ rowptr,
                                              const int* __restrict__ csrc,
                                              const float* __restrict__ dinv,
                                              const float* __restrict__ b1,
                                              float* __restrict__ h, int n) {
    int t = threadIdx.x;
    int lane = t & 63;
    int node = blockIdx.x * 4 + (t >> 6);
    if (node >= n) return;
    float di = dinv[node];
    float acc = di * xl[(size_t)node * 64 + lane];   // self-loop (x di later)
    int p = rowptr[node], p1 = rowptr[node + 1];
    for (; p + 1 < p1; p += 2) {
        int s0 = csrc[p], s1 = csrc[p + 1];
        float d0 = dinv[s0], d1 = dinv[s1];
        float v0 = xl[(size_t)s0 * 64 + lane];
        float v1 = xl[(size_t)s1 * 64 + lane];
        acc = fmaf(d0, v0, acc);
        acc = fmaf(d1, v1, acc);
    }
    if (p < p1) {
        int s0 = csrc[p];
        acc = fmaf(dinv[s0], xl[(size_t)s0 * 64 + lane], acc);
    }
    float o = fmaf(acc, di, b1[lane]);
    h[(size_t)node * 64 + lane] = fmaxf(o, 0.f);
}

// ---------------- GEMM2: [n,64] @ [64,16] ----------------

__global__ __launch_bounds__(256) void k_gemm2(const float* __restrict__ h,
                                               const float* __restrict__ W,
                                               float* __restrict__ out, int n) {
    int row = blockIdx.x * 256 + threadIdx.x;
    if (row >= n) return;
    float acc[16];
#pragma unroll
    for (int j = 0; j < 16; ++j) acc[j] = 0.f;
    const float* hr = &h[(size_t)row * 64];
#pragma unroll
    for (int k4 = 0; k4 < 16; ++k4) {
        float4 hv = *reinterpret_cast<const float4*>(&hr[k4 * 4]);
        float hvv[4] = {hv.x, hv.y, hv.z, hv.w};
#pragma unroll
        for (int kk = 0; kk < 4; ++kk) {
            const float* wr = &W[(size_t)(k4 * 4 + kk) * 16];
#pragma unroll
            for (int j = 0; j < 16; ++j) acc[j] = fmaf(hvv[kk], wr[j], acc[j]);
        }
    }
    float* op = &out[(size_t)row * 16];
#pragma unroll
    for (int j = 0; j < 16; j += 4) {
        float4 v = {acc[j], acc[j + 1], acc[j + 2], acc[j + 3]};
        *reinterpret_cast<float4*>(&op[j]) = v;
    }
}

// ---------------- Aggregation L2 (16-wide) + bias + log_softmax ----------------
// 16 lanes per node, 16 nodes per block

__global__ __launch_bounds__(256) void k_agg2(const float* __restrict__ xl,
                                              const int* __restrict__ rowptr,
                                              const int* __restrict__ csrc,
                                              const float* __restrict__ dinv,
                                              const float* __restrict__ b2,
                                              float* __restrict__ out, int n) {
    int t = threadIdx.x;
    int l = t & 15;
    int node = blockIdx.x * 16 + (t >> 4);
    if (node >= n) return;
    float di = dinv[node];
    float acc = di * xl[(size_t)node * 16 + l];
    int p1 = rowptr[node + 1];
    for (int p = rowptr[node]; p < p1; ++p) {
        int s = csrc[p];
        acc = fmaf(dinv[s], xl[(size_t)s * 16 + l], acc);
    }
    float v = fmaf(acc, di, b2[l]);
    // log_softmax across the 16-lane group
    float m = v;
#pragma unroll
    for (int o = 1; o < 16; o <<= 1) m = fmaxf(m, __shfl_xor(m, o, 16));
    float e = expf(v - m);
    float ssum = e;
#pragma unroll
    for (int o = 1; o < 16; o <<= 1) ssum += __shfl_xor(ssum, o, 16);
    out[(size_t)node * 16 + l] = v - m - logf(ssum);
}

// ---------------- launch ----------------

extern "C" void kernel_launch(void* const* d_in, const int* in_sizes, int n_in,
                              void* d_out, int out_size, void* d_ws, size_t ws_size,
                              hipStream_t stream) {
    const float* x  = (const float*)d_in[0];
    const int*   ei = (const int*)d_in[1];     // [2, E] row-major (harness contract: int32)
    const float* W1 = (const float*)d_in[2];
    const float* b1 = (const float*)d_in[3];
    const float* W2 = (const float*)d_in[4];
    const float* b2 = (const float*)d_in[5];
    float* outp = (float*)d_out;

    const int n = N_NODES;
    const int E = in_sizes[1] / 2;
    const int* src = ei;
    const int* dst = ei + E;

    // workspace carve-out (256B aligned blocks)
    size_t off = 0;
    char* base = (char*)d_ws;
    auto take = [&](size_t bytes) { size_t r = off; off += (bytes + 255) & ~(size_t)255; return r; };
    int*   cnt     = (int*)(base + take((size_t)n * 4));        // zeroed below
    int*   fill    = (int*)(base + take((size_t)n * 4));        // zeroed below (adjacent to cnt)
    int*   rowptr  = (int*)(base + take((size_t)(n + 1) * 4));
    int*   partial = (int*)(base + take(2048));
    float* dinv    = (float*)(base + take((size_t)n * 4));
    int*   csrc    = (int*)(base + take((size_t)E * 4));
    float* xl1     = (float*)(base + take((size_t)n * 64 * 4));
    float* hbuf    = (float*)(base + take((size_t)n * 64 * 4));
    float* xl2     = (float*)(base + take((size_t)n * 16 * 4));

    // zero the two counter arrays (cnt + fill are the first two blocks)
    size_t zbytes = 2 * (((size_t)n * 4 + 255) & ~(size_t)255);
    hipMemsetAsync(d_ws, 0, zbytes, stream);

    const int nbScan = (n + 255) / 256;  // 391

    k_count<<<2048, 256, 0, stream>>>(dst, E, cnt);
    k_scanA<<<nbScan, 256, 0, stream>>>(cnt, n, rowptr, partial, dinv);
    k_scanB<<<1, 512, 0, stream>>>(partial, nbScan);
    k_scanC<<<nbScan, 256, 0, stream>>>(rowptr, partial, n, E);
    k_fill<<<2048, 256, 0, stream>>>(src, dst, E, rowptr, fill, csrc);

    k_gemm1<<<(n + 255) / 256, 256, 0, stream>>>(x, W1, xl1, n);
    k_agg1<<<(n + 3) / 4, 256, 0, stream>>>(xl1, rowptr, csrc, dinv, b1, hbuf, n);
    k_gemm2<<<(n + 255) / 256, 256, 0, stream>>>(hbuf, W2, xl2, n);
    k_agg2<<<(n + 15) / 16, 256, 0, stream>>>(xl2, rowptr, csrc, dinv, b2, outp, n);
}

// Round 2
// 486.265 us; speedup vs baseline: 1.2985x; 1.2985x over previous
//
#include <hip/hip_runtime.h>
#include <hip/hip_bf16.h>

// GCN 2-layer: h = relu(Agg(x@W1)+b1); out = log_softmax(Agg(h@W2)+b2)
// Agg = D^-1/2 (A+I) D^-1/2 with dst-degree normalization.
// CSR by dst built once (count -> scan -> fill); aggregation on post-GEMM
// features (64-wide / 16-wide) -> 4x less gather traffic than pre-GEMM.

#define N_NODES 100000

// ---------------- CSR build ----------------

__global__ void k_count(const int* __restrict__ dst, int E, int* __restrict__ cnt) {
    for (int e = blockIdx.x * blockDim.x + threadIdx.x; e < E; e += gridDim.x * blockDim.x)
        atomicAdd(&cnt[dst[e]], 1);
}

__global__ void k_scanA(const int* __restrict__ cnt, int n, int* __restrict__ rowptr,
                        int* __restrict__ partial, float* __restrict__ dinv) {
    __shared__ int s[256];
    int t = threadIdx.x;
    int i = blockIdx.x * 256 + t;
    int v = (i < n) ? cnt[i] : 0;
    if (i < n) dinv[i] = rsqrtf((float)(v + 1));   // +1 self-loop; always > 0
    s[t] = v;
    __syncthreads();
    for (int off = 1; off < 256; off <<= 1) {
        int add = (t >= off) ? s[t - off] : 0;
        __syncthreads();
        s[t] += add;
        __syncthreads();
    }
    if (i < n) rowptr[i] = s[t] - v;               // exclusive
    if (t == 255) partial[blockIdx.x] = s[255];
}

__global__ void k_scanB(int* __restrict__ partial, int nb) {
    __shared__ int s[512];
    int t = threadIdx.x;
    int v = (t < nb) ? partial[t] : 0;
    s[t] = v;
    __syncthreads();
    for (int off = 1; off < 512; off <<= 1) {
        int add = (t >= off) ? s[t - off] : 0;
        __syncthreads();
        s[t] += add;
        __syncthreads();
    }
    if (t < nb) partial[t] = s[t] - v;             // exclusive block offsets
}

__global__ void k_scanC(int* __restrict__ rowptr, const int* __restrict__ partial, int n, int E) {
    int i = blockIdx.x * 256 + threadIdx.x;
    if (i < n) rowptr[i] += partial[blockIdx.x];
    if (i == 0) rowptr[n] = E;
}

__global__ void k_fill(const int* __restrict__ src, const int* __restrict__ dst, int E,
                       const int* __restrict__ rowptr, int* __restrict__ fill,
                       int* __restrict__ csrc) {
    for (int e = blockIdx.x * blockDim.x + threadIdx.x; e < E; e += gridDim.x * blockDim.x) {
        int d = dst[e];
        int pos = rowptr[d] + atomicAdd(&fill[d], 1);
        csrc[pos] = src[e];
    }
}

// ---------------- GEMM1: [n,256] @ [256,64] ----------------
// v2: register-blocked 8 rows x 8 cols per thread. Whole W1 (64KB) staged in
// LDS once; x staged transposed xtT[k][row] (16KB, BK=16). LDS = 80KB exactly
// -> 2 blocks/CU. Inner loop per k: 8 ds_read_b32 (2-way, free) +
// 2 ds_read_b128 + 64 v_fma. VALU floor ~21us.

__global__ __launch_bounds__(256, 2) void k_gemm1(const float* __restrict__ x,
                                                  const float* __restrict__ W,
                                                  float* __restrict__ out, int n) {
    __shared__ float Wl[256 * 64];    // [k][j], 64 KB
    __shared__ float xtT[16 * 256];   // [k][row], 16 KB

    int t = threadIdx.x;
    int cg = t & 7;          // col group: 8 cols
    int rg = t >> 3;         // row group: 8 rows
    int rowBase = blockIdx.x * 256;

    // stage whole W (16384 floats = 4096 float4; 16 per thread), coalesced
    {
        const float4* W4 = reinterpret_cast<const float4*>(W);
        float4* Wl4 = reinterpret_cast<float4*>(Wl);
#pragma unroll
        for (int i = 0; i < 16; ++i)
            Wl4[t + i * 256] = W4[t + i * 256];
    }

    float acc[8][8];
#pragma unroll
    for (int i = 0; i < 8; ++i)
#pragma unroll
        for (int j = 0; j < 8; ++j) acc[i][j] = 0.f;

    for (int kc = 0; kc < 256; kc += 16) {
        __syncthreads();   // covers W stage (first iter) + previous reads
        // stage x chunk transposed: 256 rows x 16 k -> xtT[k][row]
#pragma unroll
        for (int it = 0; it < 4; ++it) {
            int f4 = t + it * 256;          // 0..1023
            int r  = f4 >> 2;               // 0..255
            int c4 = f4 & 3;                // 0..3 (k/4)
            float4 v = make_float4(0.f, 0.f, 0.f, 0.f);
            int gr = rowBase + r;
            if (gr < n)
                v = *reinterpret_cast<const float4*>(&x[(size_t)gr * 256 + kc + c4 * 4]);
            xtT[(c4 * 4 + 0) * 256 + r] = v.x;
            xtT[(c4 * 4 + 1) * 256 + r] = v.y;
            xtT[(c4 * 4 + 2) * 256 + r] = v.z;
            xtT[(c4 * 4 + 3) * 256 + r] = v.w;
        }
        __syncthreads();
#pragma unroll
        for (int k = 0; k < 16; ++k) {
            float xv[8];
#pragma unroll
            for (int i = 0; i < 8; ++i) xv[i] = xtT[k * 256 + rg * 8 + i];
            float4 w0 = *reinterpret_cast<const float4*>(&Wl[(kc + k) * 64 + cg * 8]);
            float4 w1 = *reinterpret_cast<const float4*>(&Wl[(kc + k) * 64 + cg * 8 + 4]);
            float wv[8] = {w0.x, w0.y, w0.z, w0.w, w1.x, w1.y, w1.z, w1.w};
#pragma unroll
            for (int i = 0; i < 8; ++i)
#pragma unroll
                for (int j = 0; j < 8; ++j)
                    acc[i][j] = fmaf(xv[i], wv[j], acc[i][j]);
        }
    }

    // store: 8 rows x 8 cols per thread; lanes cover 256B rows contiguously
#pragma unroll
    for (int i = 0; i < 8; ++i) {
        int row = rowBase + rg * 8 + i;
        if (row < n) {
            float* op = &out[(size_t)row * 64 + cg * 8];
            float4 v0 = {acc[i][0], acc[i][1], acc[i][2], acc[i][3]};
            float4 v1 = {acc[i][4], acc[i][5], acc[i][6], acc[i][7]};
            *reinterpret_cast<float4*>(op) = v0;
            *reinterpret_cast<float4*>(op + 4) = v1;
        }
    }
}

// ---------------- Aggregation L1 (64-wide) + bias + relu ----------------
// one wave per node, lane = feature; unroll 4 for MLP

__global__ __launch_bounds__(256) void k_agg1(const float* __restrict__ xl,
                                              const int* __restrict__ rowptr,
                                              const int* __restrict__ csrc,
                                              const float* __restrict__ dinv,
                                              const float* __restrict__ b1,
                                              float* __restrict__ h, int n) {
    int t = threadIdx.x;
    int lane = t & 63;
    int node = blockIdx.x * 4 + (t >> 6);
    if (node >= n) return;
    float di = dinv[node];
    float acc = di * xl[(size_t)node * 64 + lane];   // self-loop (x di later)
    int p = rowptr[node], p1 = rowptr[node + 1];
    for (; p + 3 < p1; p += 4) {
        int s0 = csrc[p], s1 = csrc[p + 1], s2 = csrc[p + 2], s3 = csrc[p + 3];
        float d0 = dinv[s0], d1 = dinv[s1], d2 = dinv[s2], d3 = dinv[s3];
        float v0 = xl[(size_t)s0 * 64 + lane];
        float v1 = xl[(size_t)s1 * 64 + lane];
        float v2 = xl[(size_t)s2 * 64 + lane];
        float v3 = xl[(size_t)s3 * 64 + lane];
        acc = fmaf(d0, v0, acc);
        acc = fmaf(d1, v1, acc);
        acc = fmaf(d2, v2, acc);
        acc = fmaf(d3, v3, acc);
    }
    for (; p < p1; ++p) {
        int s0 = csrc[p];
        acc = fmaf(dinv[s0], xl[(size_t)s0 * 64 + lane], acc);
    }
    float o = fmaf(acc, di, b1[lane]);
    h[(size_t)node * 64 + lane] = fmaxf(o, 0.f);
}

// ---------------- GEMM2: [n,64] @ [64,16] ----------------

__global__ __launch_bounds__(256) void k_gemm2(const float* __restrict__ h,
                                               const float* __restrict__ W,
                                               float* __restrict__ out, int n) {
    int row = blockIdx.x * 256 + threadIdx.x;
    if (row >= n) return;
    float acc[16];
#pragma unroll
    for (int j = 0; j < 16; ++j) acc[j] = 0.f;
    const float* hr = &h[(size_t)row * 64];
#pragma unroll
    for (int k4 = 0; k4 < 16; ++k4) {
        float4 hv = *reinterpret_cast<const float4*>(&hr[k4 * 4]);
        float hvv[4] = {hv.x, hv.y, hv.z, hv.w};
#pragma unroll
        for (int kk = 0; kk < 4; ++kk) {
            const float* wr = &W[(size_t)(k4 * 4 + kk) * 16];
#pragma unroll
            for (int j = 0; j < 16; ++j) acc[j] = fmaf(hvv[kk], wr[j], acc[j]);
        }
    }
    float* op = &out[(size_t)row * 16];
#pragma unroll
    for (int j = 0; j < 16; j += 4) {
        float4 v = {acc[j], acc[j + 1], acc[j + 2], acc[j + 3]};
        *reinterpret_cast<float4*>(&op[j]) = v;
    }
}

// ---------------- Aggregation L2 (16-wide) + bias + log_softmax ----------------

__global__ __launch_bounds__(256) void k_agg2(const float* __restrict__ xl,
                                              const int* __restrict__ rowptr,
                                              const int* __restrict__ csrc,
                                              const float* __restrict__ dinv,
                                              const float* __restrict__ b2,
                                              float* __restrict__ out, int n) {
    int t = threadIdx.x;
    int l = t & 15;
    int node = blockIdx.x * 16 + (t >> 4);
    if (node >= n) return;
    float di = dinv[node];
    float acc = di * xl[(size_t)node * 16 + l];
    int p = rowptr[node], p1 = rowptr[node + 1];
    for (; p + 1 < p1; p += 2) {
        int s0 = csrc[p], s1 = csrc[p + 1];
        float d0 = dinv[s0], d1 = dinv[s1];
        float v0 = xl[(size_t)s0 * 16 + l];
        float v1 = xl[(size_t)s1 * 16 + l];
        acc = fmaf(d0, v0, acc);
        acc = fmaf(d1, v1, acc);
    }
    if (p < p1) {
        int s = csrc[p];
        acc = fmaf(dinv[s], xl[(size_t)s * 16 + l], acc);
    }
    float v = fmaf(acc, di, b2[l]);
    float m = v;
#pragma unroll
    for (int o = 1; o < 16; o <<= 1) m = fmaxf(m, __shfl_xor(m, o, 16));
    float e = expf(v - m);
    float ssum = e;
#pragma unroll
    for (int o = 1; o < 16; o <<= 1) ssum += __shfl_xor(ssum, o, 16);
    out[(size_t)node * 16 + l] = v - m - logf(ssum);
}

// ---------------- launch ----------------

extern "C" void kernel_launch(void* const* d_in, const int* in_sizes, int n_in,
                              void* d_out, int out_size, void* d_ws, size_t ws_size,
                              hipStream_t stream) {
    const float* x  = (const float*)d_in[0];
    const int*   ei = (const int*)d_in[1];
    const float* W1 = (const float*)d_in[2];
    const float* b1 = (const float*)d_in[3];
    const float* W2 = (const float*)d_in[4];
    const float* b2 = (const float*)d_in[5];
    float* outp = (float*)d_out;

    const int n = N_NODES;
    const int E = in_sizes[1] / 2;
    const int* src = ei;
    const int* dst = ei + E;

    size_t off = 0;
    char* base = (char*)d_ws;
    auto take = [&](size_t bytes) { size_t r = off; off += (bytes + 255) & ~(size_t)255; return r; };
    int*   cnt     = (int*)(base + take((size_t)n * 4));        // zeroed below
    int*   fill    = (int*)(base + take((size_t)n * 4));        // zeroed below (adjacent)
    int*   rowptr  = (int*)(base + take((size_t)(n + 1) * 4));
    int*   partial = (int*)(base + take(2048));
    float* dinv    = (float*)(base + take((size_t)n * 4));
    int*   csrc    = (int*)(base + take((size_t)E * 4));
    float* xl1     = (float*)(base + take((size_t)n * 64 * 4));
    float* hbuf    = (float*)(base + take((size_t)n * 64 * 4));
    float* xl2     = (float*)(base + take((size_t)n * 16 * 4));

    size_t zbytes = 2 * (((size_t)n * 4 + 255) & ~(size_t)255);
    hipMemsetAsync(d_ws, 0, zbytes, stream);

    const int nbScan = (n + 255) / 256;  // 391

    k_count<<<2048, 256, 0, stream>>>(dst, E, cnt);
    k_scanA<<<nbScan, 256, 0, stream>>>(cnt, n, rowptr, partial, dinv);
    k_scanB<<<1, 512, 0, stream>>>(partial, nbScan);
    k_scanC<<<nbScan, 256, 0, stream>>>(rowptr, partial, n, E);
    k_fill<<<2048, 256, 0, stream>>>(src, dst, E, rowptr, fill, csrc);

    k_gemm1<<<(n + 255) / 256, 256, 0, stream>>>(x, W1, xl1, n);
    k_agg1<<<(n + 3) / 4, 256, 0, stream>>>(xl1, rowptr, csrc, dinv, b1, hbuf, n);
    k_gemm2<<<(n + 255) / 256, 256, 0, stream>>>(hbuf, W2, xl2, n);
    k_agg2<<<(n + 15) / 16, 256, 0, stream>>>(xl2, rowptr, csrc, dinv, b2, outp, n);
}